// Round 3
// baseline (348.190 us; speedup 1.0000x reference)
//
#include <hip/hip_runtime.h>

// ---------------------------------------------------------------------------
// TransformerBlock: x:[2,2048,1024] fp32
//   qkv = x @ w_qkv;  attention (scale 1/sqrt(1024));  x = x + LN(attn_out)
//   ff  = relu(x@w1+b1)@w2+b2;  out = x + LN(ff)
// R10: attn re-parallelized for occupancy (R9 showed latency-prefetch null;
//     no pipe saturated; Occupancy 29% with grid=4 blocks/CU was the limit).
//     QBLK 128->64; the 4 waves of a block form 2 wave-pairs: pair kp owns a
//     DIFFERENT 512-key half (own K/V LDS tile, own staging), so grid doubles
//     to 2048 blocks (5 resident/CU at 32KB LDS). O/l pair-partials combined
//     in-block via LDS (over dead K/V tiles), then written as the same kz
//     fp32 partials as before (ln_attn unchanged). Inner tile math identical
//     to R8/R9 (swapped QK^T 32x32, in-register P via cvt_pk+permlane32,
//     XOR-swizzled K/V staging). 2-barrier staging structure (R8) restored.
//     GEMM/LN/transposes unchanged.
// ---------------------------------------------------------------------------

typedef unsigned short u16;
typedef unsigned int u32;
typedef __bf16 bf16x8 __attribute__((ext_vector_type(8)));
typedef float f32x4 __attribute__((ext_vector_type(4)));
typedef float f32x16 __attribute__((ext_vector_type(16)));
typedef u32 u32x4 __attribute__((ext_vector_type(4)));
typedef u16 u16x4 __attribute__((ext_vector_type(4)));

__device__ __forceinline__ u16 f2b(float f) {
  u32 u = __builtin_bit_cast(u32, f);
  u += 0x7fffu + ((u >> 16) & 1u);       // RNE
  return (u16)(u >> 16);
}
__device__ __forceinline__ float b2f(u16 u) {
  return __builtin_bit_cast(float, (u32)u << 16);
}

// pack 2 fp32 -> 1 dword of 2 bf16 (RNE), lo in low half
__device__ __forceinline__ u32 cvtpk(float lo, float hi) {
  u32 r;
  asm("v_cvt_pk_bf16_f32 %0, %1, %2" : "=v"(r) : "v"(lo), "v"(hi));
  return r;
}

// async global->LDS DMA, 16B per lane. LDS dest = wave-uniform base + lane*16.
__device__ __forceinline__ void gld_lds16(const u16* g, u16* l) {
  __builtin_amdgcn_global_load_lds(
      (const __attribute__((address_space(1))) u32*)g,
      (__attribute__((address_space(3))) u32*)l, 16, 0, 0);
}

// ---------------------------------------------------------------------------
__global__ __launch_bounds__(256) void convert_bf16_kernel(
    const float* __restrict__ in, u16* __restrict__ out) {
  const int idx = blockIdx.x * 256 + threadIdx.x;
  float4 v = ((const float4*)in)[idx];
  u16x4 o = { f2b(v.x), f2b(v.y), f2b(v.z), f2b(v.w) };
  ((u16x4*)out)[idx] = o;
}

// fp32[R][C] -> bf16 out[C][R]
__global__ __launch_bounds__(256) void transpose_bf16_kernel(
    const float* __restrict__ in, u16* __restrict__ out, int R, int C) {
  __shared__ float tile[32][33];
  const int cb = blockIdx.x * 32, rb = blockIdx.y * 32;
  const int c = threadIdx.x & 31;
  const int r0 = threadIdx.x >> 5;
#pragma unroll
  for (int rr = 0; rr < 32; rr += 8)
    tile[r0 + rr][c] = in[(size_t)(rb + r0 + rr) * C + cb + c];
  __syncthreads();
#pragma unroll
  for (int rr = 0; rr < 32; rr += 8)
    out[(size_t)(cb + r0 + rr) * R + rb + c] = f2b(tile[c][r0 + rr]);
}

// V part of qkv [s][d] -> vt[bh][d][s]  (bf16 copy-transpose, 64x64 tiles)
__global__ __launch_bounds__(256) void transpose_v_kernel(
    const u16* __restrict__ qkv, u16* __restrict__ vt) {
  __shared__ u16 t[64][70];
  const int bh = blockIdx.x, st = blockIdx.y;
  const int b = bh >> 4, nh = bh & 15;
  const int s0 = st * 64;
  const int r = threadIdx.x >> 3, c = (threadIdx.x & 7) << 3;
  const u16* src = qkv + (size_t)(b * 2048 + s0) * 3072 + 2048 + nh * 64;
#pragma unroll
  for (int rr = 0; rr < 64; rr += 32)
    *(u32x4*)&t[r + rr][c] = *(const u32x4*)(src + (size_t)(r + rr) * 3072 + c);
  __syncthreads();
  u16* dst = vt + ((size_t)bh * 64) * 2048 + s0;
#pragma unroll
  for (int rr = 0; rr < 64; rr += 32) {
    const int d = r + rr;
    u16 tmp[8];
#pragma unroll
    for (int j = 0; j < 8; ++j) tmp[j] = t[c + j][d];
    *(u32x4*)(dst + (size_t)d * 2048 + c) = *(u32x4*)tmp;
  }
}

// ---------------------------------------------------------------------------
// C[M,N] = A[M,K](bf16) @ Bt[N,K](bf16)^T, fp32 accum. BK=64 (32 MFMA/barrier)
// via half-split LDS [2][128][32]. XCD swizzle: requires M == 32*128.
// Split-K via gridDim.y (bf16 partials Cb/Cb1/Cb2/Cb3).
__global__ __launch_bounds__(256) void gemm_bt_kernel(
    const u16* __restrict__ A, const u16* __restrict__ Bt,
    const float* __restrict__ bias, float* __restrict__ Cf, u16* __restrict__ Cb,
    int M, int N, int K, int relu,
    u16* __restrict__ Cb1, u16* __restrict__ Cb2, u16* __restrict__ Cb3) {
  // swizzle: xcd owns 4 m-panels; 4 consecutive same-XCD blocks share n-panel
  const int bid = blockIdx.x;
  const int xcd = bid & 7;
  const int g = bid >> 3;
  const int m0 = (xcd * 4 + (g & 3)) * 128;
  const int n0 = (g >> 2) * 128;
  const int z = blockIdx.y;
  const int kn = K / (int)gridDim.y;
  if (z == 1) Cb = Cb1; else if (z == 2) Cb = Cb2; else if (z == 3) Cb = Cb3;
  const int tid = threadIdx.x;
  const int w = tid >> 6, lane = tid & 63, quad = lane >> 4, l16 = lane & 15;
  const int wm = (w & 1) * 64, wn = (w >> 1) * 64;

  __shared__ u16 As[2][128][32];   // half h = K-cols h*32..h*32+31
  __shared__ u16 Bs[2][128][32];

  f32x4 acc[4][4];
#pragma unroll
  for (int i = 0; i < 4; ++i)
#pragma unroll
    for (int j = 0; j < 4; ++j) acc[i][j] = {0.f, 0.f, 0.f, 0.f};

  // DMA map: wave w, lane l -> row w*16 + (l>>2), col (l&3)*8 within a half
  const int srow = w * 16 + (lane >> 2);
  const int scol = (lane & 3) << 3;
  const u16* Ag = A + (size_t)(m0 + srow) * K + scol + (size_t)z * kn;
  const u16* Bg = Bt + (size_t)(n0 + srow) * K + scol + (size_t)z * kn;
  const size_t rstep = (size_t)64 * K;

  for (int k0 = 0; k0 < kn; k0 += 64) {
    __syncthreads();                 // all waves done reading prev tile
    gld_lds16(Ag + k0,              &As[0][w * 16][0]);
    gld_lds16(Ag + k0 + 32,         &As[1][w * 16][0]);
    gld_lds16(Ag + rstep + k0,      &As[0][64 + w * 16][0]);
    gld_lds16(Ag + rstep + k0 + 32, &As[1][64 + w * 16][0]);
    gld_lds16(Bg + k0,              &Bs[0][w * 16][0]);
    gld_lds16(Bg + k0 + 32,         &Bs[1][w * 16][0]);
    gld_lds16(Bg + rstep + k0,      &Bs[0][64 + w * 16][0]);
    gld_lds16(Bg + rstep + k0 + 32, &Bs[1][64 + w * 16][0]);
    __syncthreads();                 // barrier drains vmcnt -> DMA visible

#pragma unroll
    for (int s = 0; s < 2; ++s) {
      bf16x8 af[4], bfr[4];
#pragma unroll
      for (int i = 0; i < 4; ++i)
        af[i] = *(const bf16x8*)&As[s][wm + i * 16 + l16][quad * 8];
#pragma unroll
      for (int j = 0; j < 4; ++j)
        bfr[j] = *(const bf16x8*)&Bs[s][wn + j * 16 + l16][quad * 8];
#pragma unroll
      for (int i = 0; i < 4; ++i)
#pragma unroll
        for (int j = 0; j < 4; ++j)
          acc[i][j] = __builtin_amdgcn_mfma_f32_16x16x32_bf16(af[i], bfr[j], acc[i][j], 0, 0, 0);
    }
  }

#pragma unroll
  for (int i = 0; i < 4; ++i) {
    const int row = m0 + wm + i * 16 + quad * 4;
#pragma unroll
    for (int j = 0; j < 4; ++j) {
      const int col = n0 + wn + j * 16 + l16;
      const float bv = bias ? bias[col] : 0.f;
#pragma unroll
      for (int r = 0; r < 4; ++r) {
        float v = acc[i][j][r] + bv;
        if (relu) v = fmaxf(v, 0.f);
        const size_t idx = (size_t)(row + r) * N + col;
        if (Cf) Cf[idx] = v;
        if (Cb) Cb[idx] = f2b(v);
      }
    }
  }
}

// ---------------------------------------------------------------------------
// Flash attention, fixed-max softmax, split over keys (kz in {0,1}).
// Block = (bh, 64 q-rows, 1024-key range). 4 waves = 2 wave-pairs:
//   qw = w&1 selects 32-q sub-block, kp = w>>1 selects 512-key half.
// Each pair stages + consumes its OWN K/V LDS tile (64 keys/round, 8 rounds).
// 32x32x16 MFMA, swapped QK^T (S^T = K.Q^T): lane owns query = lane&31.
// P fragments built in-register via cvt_pk_bf16 + permlane32_swap.
// Pair O/l partials combined in-block via LDS (over dead K/V tiles), then
// written as UNNORMALIZED fp32 O partial + l partial per kz; LN1 combines.
__global__ __launch_bounds__(256, 4) void attn_kernel(
    const u16* __restrict__ qkv, const u16* __restrict__ vt,
    float* __restrict__ Op0, float* __restrict__ Op1,
    float* __restrict__ lpart) {
  const int bh = blockIdx.x;          // b*16 + nh
  const int qt = blockIdx.y;          // 0..31 (64 q-rows each)
  const int kz = blockIdx.z;          // 0..1
  const int b = bh >> 4, nh = bh & 15;
  const int tid = threadIdx.x;
  const int w = tid >> 6, lane = tid & 63;
  const int qw = w & 1, kp = w >> 1;
  const int l32 = lane & 31, hi = lane >> 5;
  const float c2 = 0.04508422f;       // log2(e)/sqrt(1024)

  __shared__ u16 KS[2][64][64];       // [kp][key][d], chunk-swizzled
  __shared__ u16 VS[2][64][64];       // [kp][d][key], chunk-swizzled

  const size_t rs = 3072;
  const u16* qbase = qkv + (size_t)b * 2048 * rs + nh * 64;
  const u16* kbase = qbase + 1024;
  const u16* vbase = vt + (size_t)bh * 64 * 2048;
  const int q0 = qt * 64;
  const int k0beg = kz * 1024 + kp * 512;

  // staging map: lane l -> row (l>>3), 16B chunk (l&7) ^ (row&7)  (XOR swz)
  const int srow = lane >> 3;                       // 0..7
  const int scol = ((lane & 7) ^ srow) << 3;        // u16 units, swizzled

  // Q fragments to registers, pre-scaled by c2.
  // aq[ds]: Q[query = q0 + qw*32 + l32][d = 16*ds + 8*hi + j], j=0..7
  bf16x8 aq[4];
  {
    const u16* qrow = qbase + (size_t)(q0 + qw * 32 + l32) * rs + hi * 8;
#pragma unroll
    for (int ds = 0; ds < 4; ++ds) {
      u32x4 v = *(const u32x4*)(qrow + ds * 16);
      u16 ti[8], to[8];
      *(u32x4*)ti = v;
#pragma unroll
      for (int j = 0; j < 8; ++j) to[j] = f2b(b2f(ti[j]) * c2);
      *(u32x4*)to = *(u32x4*)to;
      u32x4 pk = *(u32x4*)to;
      aq[ds] = __builtin_bit_cast(bf16x8, pk);
    }
  }

  f32x16 Oacc[2];
#pragma unroll
  for (int dn = 0; dn < 2; ++dn)
#pragma unroll
    for (int i = 0; i < 16; ++i) Oacc[dn][i] = 0.f;
  float ls[4] = {0.f, 0.f, 0.f, 0.f};

#pragma unroll 1
  for (int t = 0; t < 8; ++t) {
    const int k0 = k0beg + t * 64;
    __syncthreads();                  // all waves done with prev tile
    // pair kp stages its own 64-key tile; wave qw covers half the rows
#pragma unroll
    for (int i = 0; i < 4; ++i) {
      const int rr = qw * 32 + i * 8;
      gld_lds16(kbase + (size_t)(k0 + rr + srow) * rs + scol,   &KS[kp][rr][0]);
      gld_lds16(vbase + (size_t)(rr + srow) * 2048 + k0 + scol, &VS[kp][rr][0]);
    }
    __syncthreads();                  // barrier drains vmcnt -> DMA visible

    // S^T = K . Q^T : lane holds S^T[key = 32*jt + crow(r,hi)][query = l32]
    f32x16 S[2];
#pragma unroll
    for (int jt = 0; jt < 2; ++jt)
#pragma unroll
      for (int i = 0; i < 16; ++i) S[jt][i] = 0.f;
#pragma unroll
    for (int jt = 0; jt < 2; ++jt) {
      const int krow = jt * 32 + l32;
#pragma unroll
      for (int ds = 0; ds < 4; ++ds) {
        bf16x8 kv = *(const bf16x8*)&KS[kp][krow][((2 * ds + hi) ^ (krow & 7)) << 3];
        S[jt] = __builtin_amdgcn_mfma_f32_32x32x16_bf16(kv, aq[ds], S[jt], 0, 0, 0);
      }
    }

    // p = exp2(S^T); build PV A-fragments in-register.
    // pa[ks] = P[query = l32][key = 16*ks + 8*hi + j], ks = 2*jt + bq
    bf16x8 pa[4];
#pragma unroll
    for (int jt = 0; jt < 2; ++jt) {
      float p[16];
#pragma unroll
      for (int r = 0; r < 16; ++r) {
        p[r] = exp2f(S[jt][r]);
        ls[r & 3] += p[r];
      }
#pragma unroll
      for (int bq = 0; bq < 2; ++bq) {
        u32 x0 = cvtpk(p[8 * bq + 0], p[8 * bq + 1]);
        u32 y0 = cvtpk(p[8 * bq + 4], p[8 * bq + 5]);
        u32 x1 = cvtpk(p[8 * bq + 2], p[8 * bq + 3]);
        u32 y1 = cvtpk(p[8 * bq + 6], p[8 * bq + 7]);
        // swap hi-half(x) <-> lo-half(y): x' = [x_lo|y_lo], y' = [x_hi|y_hi]
        asm("v_permlane32_swap_b32 %0, %1" : "+v"(x0), "+v"(y0));
        asm("v_permlane32_swap_b32 %0, %1" : "+v"(x1), "+v"(y1));
        u32x4 dw = {x0, x1, y0, y1};  // keys {0,1},{2,3},{4,5},{6,7} (+8hi)
        pa[2 * jt + bq] = __builtin_bit_cast(bf16x8, dw);
      }
    }

    // O += P V : lane holds O[query = crow(r,hi)][d = dn*32 + l32]
#pragma unroll
    for (int dn = 0; dn < 2; ++dn) {
      const int vrow = dn * 32 + l32;
#pragma unroll
      for (int ks = 0; ks < 4; ++ks) {
        bf16x8 vv = *(const bf16x8*)&VS[kp][vrow][((2 * ks + hi) ^ (vrow & 7)) << 3];
        Oacc[dn] = __builtin_amdgcn_mfma_f32_32x32x16_bf16(pa[ks], vv, Oacc[dn], 0, 0, 0);
      }
    }
  }

  // per-wave l over its 512 keys: fold hi halves
  float lsum = (ls[0] + ls[1]) + (ls[2] + ls[3]);
  lsum += __shfl_xor(lsum, 32);

  // pair combine via LDS (K/V tiles dead): shO [2][32][64] f32 over KS,
  // shL [2][32] f32 over VS.
  __syncthreads();
  float* shO = (float*)&KS[0][0][0];
  float* shL = (float*)&VS[0][0][0];
  if (kp == 1) {
#pragma unroll
    for (int r = 0; r < 16; ++r) {
      const int qr = (r & 3) + 8 * (r >> 2) + 4 * hi;
      shO[(qw * 32 + qr) * 64 + l32]      = Oacc[0][r];
      shO[(qw * 32 + qr) * 64 + 32 + l32] = Oacc[1][r];
    }
    if (lane < 32) shL[qw * 32 + l32] = lsum;
  }
  __syncthreads();
  if (kp == 0) {
    float* opart = kz ? Op1 : Op0;
    float* obase = opart + (size_t)b * 2048 * 1024 + (size_t)nh * 64;
    float* lbase = lpart + (size_t)kz * 4096 * 16 + (size_t)b * 2048 * 16 + nh;
#pragma unroll
    for (int r = 0; r < 16; ++r) {
      const int qr = (r & 3) + 8 * (r >> 2) + 4 * hi;
      const int qrow = q0 + qw * 32 + qr;
      obase[(size_t)qrow * 1024 + l32]      = Oacc[0][r] + shO[(qw * 32 + qr) * 64 + l32];
      obase[(size_t)qrow * 1024 + 32 + l32] = Oacc[1][r] + shO[(qw * 32 + qr) * 64 + 32 + l32];
    }
    if (lane < 32)
      lbase[(size_t)(q0 + qw * 32 + l32) * 16] = lsum + shL[qw * 32 + l32];
  }
}

// ---------------------------------------------------------------------------
// x1 = xres + LN((O0+O1)/(l0+l1))*g + b ; writes fp32 + bf16
__global__ __launch_bounds__(256) void ln_attn_kernel(
    const float* __restrict__ O0, const float* __restrict__ O1,
    const float* __restrict__ l0, const float* __restrict__ l1,
    const float* __restrict__ xres, const float* __restrict__ g,
    const float* __restrict__ bb, float* __restrict__ outf,
    u16* __restrict__ outb) {
  const int row = blockIdx.x;
  const int tid = threadIdx.x;
  const int w = tid >> 6, lane = tid & 63;
  const int head = tid >> 4;
  float4 a0 = ((const float4*)(O0 + (size_t)row * 1024))[tid];
  float4 a1 = ((const float4*)(O1 + (size_t)row * 1024))[tid];
  const float inv = 1.f / (l0[row * 16 + head] + l1[row * 16 + head]);
  float4 v;
  v.x = (a0.x + a1.x) * inv;
  v.y = (a0.y + a1.y) * inv;
  v.z = (a0.z + a1.z) * inv;
  v.w = (a0.w + a1.w) * inv;
  float s = v.x + v.y + v.z + v.w;
  float s2 = v.x * v.x + v.y * v.y + v.z * v.z + v.w * v.w;
#pragma unroll
  for (int off = 32; off > 0; off >>= 1) {
    s += __shfl_xor(s, off);
    s2 += __shfl_xor(s2, off);
  }
  __shared__ float red[8];
  if (lane == 0) { red[w] = s; red[4 + w] = s2; }
  __syncthreads();
  s = red[0] + red[1] + red[2] + red[3];
  s2 = red[4] + red[5] + red[6] + red[7];
  const float mu = s * (1.f / 1024.f);
  const float var = s2 * (1.f / 1024.f) - mu * mu;
  const float rstd = rsqrtf(var + 1e-5f);
  float4 xr = ((const float4*)(xres + (size_t)row * 1024))[tid];
  float4 gv = ((const float4*)g)[tid];
  float4 bv = ((const float4*)bb)[tid];
  float4 o;
  o.x = xr.x + (v.x - mu) * rstd * gv.x + bv.x;
  o.y = xr.y + (v.y - mu) * rstd * gv.y + bv.y;
  o.z = xr.z + (v.z - mu) * rstd * gv.z + bv.z;
  o.w = xr.w + (v.w - mu) * rstd * gv.w + bv.w;
  ((float4*)(outf + (size_t)row * 1024))[tid] = o;
  u16x4 ob = { f2b(o.x), f2b(o.y), f2b(o.z), f2b(o.w) };
  *(u16x4*)(outb + (size_t)row * 1024 + (size_t)tid * 4) = ob;
}

// ---------------------------------------------------------------------------
// out = xres + LN(p0+p1+p2+p3 + bias)*g + b  (FFN2 split-K combine), fp32 out
__global__ __launch_bounds__(256) void ln_ffn_kernel(
    const u16* __restrict__ p0, const u16* __restrict__ p1,
    const u16* __restrict__ p2, const u16* __restrict__ p3,
    const float* __restrict__ bias, const float* __restrict__ xres,
    const float* __restrict__ g, const float* __restrict__ bb,
    float* __restrict__ outf) {
  const int row = blockIdx.x;
  const int tid = threadIdx.x;
  const int w = tid >> 6, lane = tid & 63;
  u16x4 a0 = ((const u16x4*)(p0 + (size_t)row * 1024))[tid];
  u16x4 a1 = ((const u16x4*)(p1 + (size_t)row * 1024))[tid];
  u16x4 a2 = ((const u16x4*)(p2 + (size_t)row * 1024))[tid];
  u16x4 a3 = ((const u16x4*)(p3 + (size_t)row * 1024))[tid];
  float4 bv4 = ((const float4*)bias)[tid];
  float4 v;
  v.x = (b2f(a0[0]) + b2f(a1[0])) + (b2f(a2[0]) + b2f(a3[0])) + bv4.x;
  v.y = (b2f(a0[1]) + b2f(a1[1])) + (b2f(a2[1]) + b2f(a3[1])) + bv4.y;
  v.z = (b2f(a0[2]) + b2f(a1[2])) + (b2f(a2[2]) + b2f(a3[2])) + bv4.z;
  v.w = (b2f(a0[3]) + b2f(a1[3])) + (b2f(a2[3]) + b2f(a3[3])) + bv4.w;
  float s = v.x + v.y + v.z + v.w;
  float s2 = v.x * v.x + v.y * v.y + v.z * v.z + v.w * v.w;
#pragma unroll
  for (int off = 32; off > 0; off >>= 1) {
    s += __shfl_xor(s, off);
    s2 += __shfl_xor(s2, off);
  }
  __shared__ float red[8];
  if (lane == 0) { red[w] = s; red[4 + w] = s2; }
  __syncthreads();
  s = red[0] + red[1] + red[2] + red[3];
  s2 = red[4] + red[5] + red[6] + red[7];
  const float mu = s * (1.f / 1024.f);
  const float var = s2 * (1.f / 1024.f) - mu * mu;
  const float rstd = rsqrtf(var + 1e-5f);
  float4 xr = ((const float4*)(xres + (size_t)row * 1024))[tid];
  float4 gv = ((const float4*)g)[tid];
  float4 bv = ((const float4*)bb)[tid];
  float4 o;
  o.x = xr.x + (v.x - mu) * rstd * gv.x + bv.x;
  o.y = xr.y + (v.y - mu) * rstd * gv.y + bv.y;
  o.z = xr.z + (v.z - mu) * rstd * gv.z + bv.z;
  o.w = xr.w + (v.w - mu) * rstd * gv.w + bv.w;
  ((float4*)(outf + (size_t)row * 1024))[tid] = o;
}

// ---------------------------------------------------------------------------
extern "C" void kernel_launch(void* const* d_in, const int* in_sizes, int n_in,
                              void* d_out, int out_size, void* d_ws, size_t ws_size,
                              hipStream_t stream) {
  const float* x     = (const float*)d_in[0];
  const float* w_qkv = (const float*)d_in[1];
  const float* ln1_g = (const float*)d_in[2];
  const float* ln1_b = (const float*)d_in[3];
  const float* w1    = (const float*)d_in[4];
  const float* b1    = (const float*)d_in[5];
  const float* w2    = (const float*)d_in[6];
  const float* b2    = (const float*)d_in[7];
  const float* ln2_g = (const float*)d_in[8];
  const float* ln2_b = (const float*)d_in[9];
  float* out = (float*)d_out;
  char* ws = (char*)d_ws;

  // workspace (lifetime-aliased; max end = 98,566,144 B):
  u16*   xb    = (u16*)(ws + 0);              // [0,8.4M)     dead after qkv gemm
  u16*   wqkvT = (u16*)(ws + 8388608);        // [8.4,14.7M)  dead after qkv gemm
  u16*   qkvb  = (u16*)(ws + 31457280);       // [31.5,56.6M) dead after attn
  u16*   vT    = (u16*)(ws + 56623104);       // [56.6,73.4M) dead after attn
  float* Op0   = (float*)(ws + 0);            // [0,16.8M)    attn partial 0 (over dead xb/wqkvT)
  float* Op1   = (float*)(ws + 73400320);     // [73.4,90.2M) attn partial 1
  float* lp    = (float*)(ws + 90177536);     // [90.2,90.7M) l partials (2x256KB)
  float* x1    = (float*)(ws + 31457280);     // [31.5,48.2M) over dead qkvb (after attn)
  u16*   x1b   = (u16*)(ws + 48234496);       // [48.2,56.6M) over dead qkvb; dead after FFN1
  u16*   w1T   = (u16*)(ws + 14680064);       // [14.7,23.1M) written after LN1 (over dead Op0)
  u16*   w2T   = (u16*)(ws + 23068672);       // [23.1,31.5M) written after LN1
  u16*   h1    = (u16*)(ws + 56623104);       // [56.6,90.2M) over dead vT+Op1
  u16*   fp0   = (u16*)(ws + 0);              // FFN2 partials (over dead Op0/lp/x1b)
  u16*   fp1   = (u16*)(ws + 8388608);
  u16*   fp2   = (u16*)(ws + 48234496);
  u16*   fp3   = (u16*)(ws + 90177536);

  convert_bf16_kernel<<<4096, 256, 0, stream>>>(x, xb);
  transpose_bf16_kernel<<<dim3(96, 32), 256, 0, stream>>>(w_qkv, wqkvT, 1024, 3072);

  // qkv: M=4096 N=3072 K=1024; swizzled grid 32*24 blocks
  gemm_bt_kernel<<<dim3(32 * 24, 1), 256, 0, stream>>>(
      xb, wqkvT, nullptr, nullptr, qkvb, 4096, 3072, 1024, 0,
      nullptr, nullptr, nullptr);
  transpose_v_kernel<<<dim3(32, 32), 256, 0, stream>>>(qkvb, vT);
  attn_kernel<<<dim3(32, 32, 2), 256, 0, stream>>>(qkvb, vT, Op0, Op1, lp);

  ln_attn_kernel<<<4096, 256, 0, stream>>>(
      Op0, Op1, lp, lp + 4096 * 16, x, ln1_g, ln1_b, x1, x1b);

  transpose_bf16_kernel<<<dim3(128, 32), 256, 0, stream>>>(w1, w1T, 1024, 4096);
  transpose_bf16_kernel<<<dim3(32, 128), 256, 0, stream>>>(w2, w2T, 4096, 1024);

  // FFN1: M=4096 N=4096 K=1024
  gemm_bt_kernel<<<dim3(32 * 32, 1), 256, 0, stream>>>(
      x1b, w1T, b1, nullptr, h1, 4096, 4096, 1024, 1,
      nullptr, nullptr, nullptr);
  // FFN2: M=4096 N=1024 K=4096, split-K=4 via gridDim.y
  gemm_bt_kernel<<<dim3(32 * 8, 4), 256, 0, stream>>>(
      h1, w2T, nullptr, nullptr, fp0, 4096, 1024, 4096, 0,
      fp1, fp2, fp3);

  ln_ffn_kernel<<<4096, 256, 0, stream>>>(
      fp0, fp1, fp2, fp3, b2, x1, ln2_g, ln2_b, out);
}

// Round 4
// 325.708 us; speedup vs baseline: 1.0690x; 1.0690x over previous
//
#include <hip/hip_runtime.h>

// ---------------------------------------------------------------------------
// TransformerBlock: x:[2,2048,1024] fp32
//   qkv = x @ w_qkv;  attention (scale 1/sqrt(1024));  x = x + LN(attn_out)
//   ff  = relu(x@w1+b1)@w2+b2;  out = x + LN(ff)
// R11: GEMMs rewritten to the 256^2 8-phase-class schedule (T2+T3+T4+T5):
//     BM=BN=256, BK=32, 8 waves (2Mx4N, 512 thr), 4 LDS buffers (128KB),
//     staging runs TWO K-tiles ahead -> counted s_waitcnt vmcnt(4) at each
//     tile's last phase (never 0 in main loop). Per tile 2 phases:
//     {ds_read subtile | stage 2 gld_lds | barrier | lgkmcnt(0) | setprio(1)
//      16 MFMA | setprio(0) | barrier}. Chunk-XOR swizzle c^=(row&3) on BOTH
//     the pre-swizzled global DMA source and fragment reads (rule 21) ->
//     8-accesses/bank minimum on ds_read_b128. All 3 GEMMs use it (K-per-
//     block = 1024 = 32 tiles hardcoded; FFN2 via split-K gridDim.y=4).
//     attn reverted to R8 (best measured, 61.6us; R9 prefetch and R10
//     occupancy-split both null/negative). LN/transposes unchanged.
// ---------------------------------------------------------------------------

typedef unsigned short u16;
typedef unsigned int u32;
typedef __bf16 bf16x8 __attribute__((ext_vector_type(8)));
typedef float f32x4 __attribute__((ext_vector_type(4)));
typedef float f32x16 __attribute__((ext_vector_type(16)));
typedef u32 u32x4 __attribute__((ext_vector_type(4)));
typedef u16 u16x4 __attribute__((ext_vector_type(4)));

__device__ __forceinline__ u16 f2b(float f) {
  u32 u = __builtin_bit_cast(u32, f);
  u += 0x7fffu + ((u >> 16) & 1u);       // RNE
  return (u16)(u >> 16);
}
__device__ __forceinline__ float b2f(u16 u) {
  return __builtin_bit_cast(float, (u32)u << 16);
}

// pack 2 fp32 -> 1 dword of 2 bf16 (RNE), lo in low half
__device__ __forceinline__ u32 cvtpk(float lo, float hi) {
  u32 r;
  asm("v_cvt_pk_bf16_f32 %0, %1, %2" : "=v"(r) : "v"(lo), "v"(hi));
  return r;
}

// async global->LDS DMA, 16B per lane. LDS dest = wave-uniform base + lane*16.
__device__ __forceinline__ void gld_lds16(const u16* g, u16* l) {
  __builtin_amdgcn_global_load_lds(
      (const __attribute__((address_space(1))) u32*)g,
      (__attribute__((address_space(3))) u32*)l, 16, 0, 0);
}

// ---------------------------------------------------------------------------
__global__ __launch_bounds__(256) void convert_bf16_kernel(
    const float* __restrict__ in, u16* __restrict__ out) {
  const int idx = blockIdx.x * 256 + threadIdx.x;
  float4 v = ((const float4*)in)[idx];
  u16x4 o = { f2b(v.x), f2b(v.y), f2b(v.z), f2b(v.w) };
  ((u16x4*)out)[idx] = o;
}

// fp32[R][C] -> bf16 out[C][R]
__global__ __launch_bounds__(256) void transpose_bf16_kernel(
    const float* __restrict__ in, u16* __restrict__ out, int R, int C) {
  __shared__ float tile[32][33];
  const int cb = blockIdx.x * 32, rb = blockIdx.y * 32;
  const int c = threadIdx.x & 31;
  const int r0 = threadIdx.x >> 5;
#pragma unroll
  for (int rr = 0; rr < 32; rr += 8)
    tile[r0 + rr][c] = in[(size_t)(rb + r0 + rr) * C + cb + c];
  __syncthreads();
#pragma unroll
  for (int rr = 0; rr < 32; rr += 8)
    out[(size_t)(cb + r0 + rr) * R + rb + c] = f2b(tile[c][r0 + rr]);
}

// V part of qkv [s][d] -> vt[bh][d][s]  (bf16 copy-transpose, 64x64 tiles)
__global__ __launch_bounds__(256) void transpose_v_kernel(
    const u16* __restrict__ qkv, u16* __restrict__ vt) {
  __shared__ u16 t[64][70];
  const int bh = blockIdx.x, st = blockIdx.y;
  const int b = bh >> 4, nh = bh & 15;
  const int s0 = st * 64;
  const int r = threadIdx.x >> 3, c = (threadIdx.x & 7) << 3;
  const u16* src = qkv + (size_t)(b * 2048 + s0) * 3072 + 2048 + nh * 64;
#pragma unroll
  for (int rr = 0; rr < 64; rr += 32)
    *(u32x4*)&t[r + rr][c] = *(const u32x4*)(src + (size_t)(r + rr) * 3072 + c);
  __syncthreads();
  u16* dst = vt + ((size_t)bh * 64) * 2048 + s0;
#pragma unroll
  for (int rr = 0; rr < 64; rr += 32) {
    const int d = r + rr;
    u16 tmp[8];
#pragma unroll
    for (int j = 0; j < 8; ++j) tmp[j] = t[c + j][d];
    *(u32x4*)(dst + (size_t)d * 2048 + c) = *(u32x4*)tmp;
  }
}

// ---------------------------------------------------------------------------
// C[M,N] = A[M,K](bf16) @ Bt[N,K](bf16)^T, fp32 accum, bf16 out.
// 256x256 tile, BK=32, 8 waves (wm=w>>2 in {0,1}: 128 rows; wn=w&3: 64 cols).
// K-per-block hardcoded 1024 (32 tiles); split-K via gridDim.y (z*1024 K-off).
// 4 LDS buffers; tile t+2 staged during tile t; vmcnt(4) ledger (see header).
// Requires M%256==0, N%256==0, gridDim.x%8==0.
#define GTILE(T, BUF, T2, VM)                                                 \
  {                                                                           \
    const u16(*Ab)[32] = As[BUF];                                             \
    const u16(*Bb)[32] = Bs[BUF];                                             \
    bf16x8 af[4], bf[4];                                                      \
    _Pragma("unroll") for (int nr = 0; nr < 4; ++nr)                          \
        bf[nr] = *(const bf16x8*)&Bb[wn * 64 + nr * 16 + l16][cRd];           \
    _Pragma("unroll") for (int mr = 0; mr < 4; ++mr)                          \
        af[mr] = *(const bf16x8*)&Ab[wm * 128 + mr * 16 + l16][cRd];          \
    if ((T2) >= 0) {                                                          \
      gld_lds16(Ag + (size_t)(T2) * 32,         &As[(T2) & 3][w * 16][0]);    \
      gld_lds16(Ag + rstep + (size_t)(T2) * 32, &As[(T2) & 3][128 + w * 16][0]);\
    }                                                                         \
    __builtin_amdgcn_sched_barrier(0);                                        \
    __builtin_amdgcn_s_barrier();                                             \
    asm volatile("s_waitcnt lgkmcnt(0)" ::: "memory");                        \
    __builtin_amdgcn_sched_barrier(0);                                        \
    __builtin_amdgcn_s_setprio(1);                                            \
    _Pragma("unroll") for (int mr = 0; mr < 4; ++mr)                          \
        _Pragma("unroll") for (int nr = 0; nr < 4; ++nr)                      \
            acc[mr][nr] = __builtin_amdgcn_mfma_f32_16x16x32_bf16(            \
                af[mr], bf[nr], acc[mr][nr], 0, 0, 0);                        \
    __builtin_amdgcn_s_setprio(0);                                            \
    __builtin_amdgcn_s_barrier();                                             \
    _Pragma("unroll") for (int mr = 0; mr < 4; ++mr)                          \
        af[mr] = *(const bf16x8*)&Ab[wm * 128 + 64 + mr * 16 + l16][cRd];     \
    if ((T2) >= 0) {                                                          \
      gld_lds16(Bg + (size_t)(T2) * 32,         &Bs[(T2) & 3][w * 16][0]);    \
      gld_lds16(Bg + rstep + (size_t)(T2) * 32, &Bs[(T2) & 3][128 + w * 16][0]);\
    }                                                                         \
    __builtin_amdgcn_sched_barrier(0);                                        \
    __builtin_amdgcn_s_barrier();                                             \
    asm volatile("s_waitcnt lgkmcnt(0)" ::: "memory");                        \
    __builtin_amdgcn_sched_barrier(0);                                        \
    __builtin_amdgcn_s_setprio(1);                                            \
    _Pragma("unroll") for (int mr = 0; mr < 4; ++mr)                          \
        _Pragma("unroll") for (int nr = 0; nr < 4; ++nr)                      \
            acc[4 + mr][nr] = __builtin_amdgcn_mfma_f32_16x16x32_bf16(        \
                af[mr], bf[nr], acc[4 + mr][nr], 0, 0, 0);                    \
    __builtin_amdgcn_s_setprio(0);                                            \
    if ((VM) == 4) asm volatile("s_waitcnt vmcnt(4)" ::: "memory");           \
    else if ((VM) == 0) asm volatile("s_waitcnt vmcnt(0)" ::: "memory");      \
    __builtin_amdgcn_s_barrier();                                             \
  }

__global__ __launch_bounds__(512) void gemm256_kernel(
    const u16* __restrict__ A, const u16* __restrict__ Bt,
    const float* __restrict__ bias, u16* __restrict__ Cb,
    int M, int N, int K, int relu,
    u16* __restrict__ Cb1, u16* __restrict__ Cb2, u16* __restrict__ Cb3) {
  // XCD-chunked bijective swizzle (gridDim.x % 8 == 0): consecutive blocks in
  // an XCD share the A row-panel (L2-resident), sweep n.
  const int nN = N >> 8;
  const int lin = (blockIdx.x & 7) * ((int)gridDim.x >> 3) + (blockIdx.x >> 3);
  const int m0 = (lin / nN) << 8;
  const int n0 = (lin % nN) << 8;
  const int z = blockIdx.y;
  if (z == 1) Cb = Cb1; else if (z == 2) Cb = Cb2; else if (z == 3) Cb = Cb3;

  const int tid = threadIdx.x;
  const int w = tid >> 6, lane = tid & 63;
  const int quad = lane >> 4, l16 = lane & 15;
  const int wm = w >> 2, wn = w & 3;

  __shared__ u16 As[4][256][32];      // 64KB: K-cols t*32..t*32+31, swizzled
  __shared__ u16 Bs[4][256][32];      // 64KB

  f32x4 acc[8][4];
#pragma unroll
  for (int i = 0; i < 8; ++i)
#pragma unroll
    for (int j = 0; j < 4; ++j) acc[i][j] = {0.f, 0.f, 0.f, 0.f};

  // staging: per gld_lds, wave w covers 16 rows (rows w*16+(l>>2), +issue*128);
  // pre-swizzled global chunk = (l&3) ^ (row&3) so LDS[row][c] holds global
  // chunk c ^ (row&3)  (involution; reads apply the same XOR).
  const int srow = lane >> 2;                               // 0..15
  const int scol = (((lane & 3) ^ (srow & 3)) << 3);        // u16 units
  const u16* Ag = A + (size_t)(m0 + w * 16 + srow) * K + (size_t)z * 1024 + scol;
  const u16* Bg = Bt + (size_t)(n0 + w * 16 + srow) * K + (size_t)z * 1024 + scol;
  const size_t rstep = (size_t)128 * K;

  // fragment-read swizzled chunk: row&3 == l16&3 for all frag rows
  const int cRd = ((quad ^ (l16 & 3)) << 3);                // u16 units

  // prologue: stage tiles 0 and 1; vmcnt(4) -> tile 0 resident, tile 1 in flight
  gld_lds16(Ag,              &As[0][w * 16][0]);
  gld_lds16(Ag + rstep,      &As[0][128 + w * 16][0]);
  gld_lds16(Bg,              &Bs[0][w * 16][0]);
  gld_lds16(Bg + rstep,      &Bs[0][128 + w * 16][0]);
  gld_lds16(Ag + 32,         &As[1][w * 16][0]);
  gld_lds16(Ag + rstep + 32, &As[1][128 + w * 16][0]);
  gld_lds16(Bg + 32,         &Bs[1][w * 16][0]);
  gld_lds16(Bg + rstep + 32, &Bs[1][128 + w * 16][0]);
  asm volatile("s_waitcnt vmcnt(4)" ::: "memory");
  __builtin_amdgcn_s_barrier();

  for (int tt = 0; tt < 7; ++tt) {
    const int t = tt * 4;
    GTILE(t + 0, 0, t + 2, 4)
    GTILE(t + 1, 1, t + 3, 4)
    GTILE(t + 2, 2, t + 4, 4)
    GTILE(t + 3, 3, t + 5, 4)
  }
  GTILE(28, 0, 30, 4)
  GTILE(29, 1, 31, 4)
  GTILE(30, 2, -1, 0)
  GTILE(31, 3, -1, -1)

  // epilogue: wave writes 128 rows x 64 cols
#pragma unroll
  for (int mr = 0; mr < 8; ++mr) {
    const int row = m0 + wm * 128 + mr * 16 + quad * 4;
#pragma unroll
    for (int nr = 0; nr < 4; ++nr) {
      const int col = n0 + wn * 64 + nr * 16 + l16;
      const float bv = bias ? bias[col] : 0.f;
#pragma unroll
      for (int r = 0; r < 4; ++r) {
        float v = acc[mr][nr][r] + bv;
        if (relu) v = fmaxf(v, 0.f);
        Cb[(size_t)(row + r) * N + col] = f2b(v);
      }
    }
  }
}

// ---------------------------------------------------------------------------
// Flash attention (R8 version), fixed-max softmax, split over keys (kz 0/1).
// Block = (bh, 128 q-rows, 1024-key range); 4 waves x 32 q-rows.
// 32x32x16 MFMA, swapped QK^T (S^T = K.Q^T): lane owns query = lane&31.
// P fragments built in-register via cvt_pk_bf16 + permlane32_swap.
// Writes UNNORMALIZED O partial (fp32) + l partial; LN1 combines.
__global__ __launch_bounds__(256, 4) void attn_kernel(
    const u16* __restrict__ qkv, const u16* __restrict__ vt,
    float* __restrict__ Op0, float* __restrict__ Op1,
    float* __restrict__ lpart) {
  const int bh = blockIdx.x;          // b*16 + nh
  const int qt = blockIdx.y;          // 0..15
  const int kz = blockIdx.z;          // 0..1
  const int b = bh >> 4, nh = bh & 15;
  const int tid = threadIdx.x;
  const int w = tid >> 6, lane = tid & 63;
  const int l32 = lane & 31, hi = lane >> 5;
  const float c2 = 0.04508422f;       // log2(e)/sqrt(1024)

  __shared__ u16 KS[64][64];          // K tile [key][d], chunk-swizzled
  __shared__ u16 VS[64][64];          // V^T tile [d][key], chunk-swizzled

  const size_t rs = 3072;
  const u16* qbase = qkv + (size_t)b * 2048 * rs + nh * 64;
  const u16* kbase = qbase + 1024;
  const u16* vbase = vt + (size_t)bh * 64 * 2048;
  const int q0 = qt * 128;
  const int k0beg = kz * 1024;

  // Q fragments to registers, pre-scaled by c2.
  bf16x8 aq[4];
  {
    const u16* qrow = qbase + (size_t)(q0 + w * 32 + l32) * rs + hi * 8;
#pragma unroll
    for (int ds = 0; ds < 4; ++ds) {
      u32x4 v = *(const u32x4*)(qrow + ds * 16);
      u16 ti[8], to[8];
      *(u32x4*)ti = v;
#pragma unroll
      for (int j = 0; j < 8; ++j) to[j] = f2b(b2f(ti[j]) * c2);
      u32x4 pk = *(u32x4*)to;
      aq[ds] = __builtin_bit_cast(bf16x8, pk);
    }
  }

  f32x16 Oacc[2];
#pragma unroll
  for (int dn = 0; dn < 2; ++dn)
#pragma unroll
    for (int i = 0; i < 16; ++i) Oacc[dn][i] = 0.f;
  float ls[4] = {0.f, 0.f, 0.f, 0.f};

  // staging map: lane l -> row (l>>3), 16B chunk (l&7) ^ (row&7)  (XOR swz)
  const int srow = lane >> 3;                       // 0..7
  const int scol = ((lane & 7) ^ srow) << 3;        // u16 units, swizzled

#pragma unroll 1
  for (int t = 0; t < 16; ++t) {
    const int k0 = k0beg + t * 64;
    __syncthreads();                  // all waves done with prev tile
    gld_lds16(kbase + (size_t)(k0 + w * 16 + srow) * rs + scol,       &KS[w * 16][0]);
    gld_lds16(kbase + (size_t)(k0 + w * 16 + 8 + srow) * rs + scol,   &KS[w * 16 + 8][0]);
    gld_lds16(vbase + (size_t)(w * 16 + srow) * 2048 + k0 + scol,     &VS[w * 16][0]);
    gld_lds16(vbase + (size_t)(w * 16 + 8 + srow) * 2048 + k0 + scol, &VS[w * 16 + 8][0]);
    __syncthreads();                  // barrier drains vmcnt -> DMA visible

    // S^T = K . Q^T : lane holds S^T[key = 32*jt + crow(r,hi)][query = l32]
    f32x16 S[2];
#pragma unroll
    for (int jt = 0; jt < 2; ++jt)
#pragma unroll
      for (int i = 0; i < 16; ++i) S[jt][i] = 0.f;
#pragma unroll
    for (int jt = 0; jt < 2; ++jt) {
      const int krow = jt * 32 + l32;
#pragma unroll
      for (int ds = 0; ds < 4; ++ds) {
        bf16x8 kv = *(const bf16x8*)&KS[krow][((2 * ds + hi) ^ (krow & 7)) << 3];
        S[jt] = __builtin_amdgcn_mfma_f32_32x32x16_bf16(kv, aq[ds], S[jt], 0, 0, 0);
      }
    }

    // p = exp2(S^T); build PV A-fragments in-register.
    bf16x8 pa[4];
#pragma unroll
    for (int jt = 0; jt < 2; ++jt) {
      float p[16];
#pragma unroll
      for (int r = 0; r < 16; ++r) {
        p[r] = exp2f(S[jt][r]);
        ls[r & 3] += p[r];
      }
#pragma unroll
      for (int bq = 0; bq < 2; ++bq) {
        u32 x0 = cvtpk(p[8 * bq + 0], p[8 * bq + 1]);
        u32 y0 = cvtpk(p[8 * bq + 4], p[8 * bq + 5]);
        u32 x1 = cvtpk(p[8 * bq + 2], p[8 * bq + 3]);
        u32 y1 = cvtpk(p[8 * bq + 6], p[8 * bq + 7]);
        asm("v_permlane32_swap_b32 %0, %1" : "+v"(x0), "+v"(y0));
        asm("v_permlane32_swap_b32 %0, %1" : "+v"(x1), "+v"(y1));
        u32x4 dw = {x0, x1, y0, y1};  // keys {0,1},{2,3},{4,5},{6,7} (+8hi)
        pa[2 * jt + bq] = __builtin_bit_cast(bf16x8, dw);
      }
    }

    // O += P V : lane holds O[query = crow(r,hi)][d = dn*32 + l32]
#pragma unroll
    for (int dn = 0; dn < 2; ++dn) {
      const int vrow = dn * 32 + l32;
#pragma unroll
      for (int ks = 0; ks < 4; ++ks) {
        bf16x8 vv = *(const bf16x8*)&VS[vrow][((2 * ks + hi) ^ (vrow & 7)) << 3];
        Oacc[dn] = __builtin_amdgcn_mfma_f32_32x32x16_bf16(pa[ks], vv, Oacc[dn], 0, 0, 0);
      }
    }
  }

  // l: per-lane partial covers this hi's keys; add partner half (lane^32)
  float lsum = (ls[0] + ls[1]) + (ls[2] + ls[3]);
  const float ltot = lsum + __shfl_xor(lsum, 32);

  float* opart = kz ? Op1 : Op0;
  float* obase = opart + (size_t)b * 2048 * 1024 + (size_t)nh * 64;
  float* lbase = lpart + (size_t)kz * 4096 * 16 + (size_t)b * 2048 * 16 + nh;
#pragma unroll
  for (int r = 0; r < 16; ++r) {
    const int qrow = q0 + w * 32 + (r & 3) + 8 * (r >> 2) + 4 * hi;
#pragma unroll
    for (int dn = 0; dn < 2; ++dn)
      obase[(size_t)qrow * 1024 + dn * 32 + l32] = Oacc[dn][r];
  }
  if (lane < 32) lbase[(size_t)(q0 + w * 32 + l32) * 16] = ltot;
}

// ---------------------------------------------------------------------------
// x1 = xres + LN((O0+O1)/(l0+l1))*g + b ; writes fp32 + bf16
__global__ __launch_bounds__(256) void ln_attn_kernel(
    const float* __restrict__ O0, const float* __restrict__ O1,
    const float* __restrict__ l0, const float* __restrict__ l1,
    const float* __restrict__ xres, const float* __restrict__ g,
    const float* __restrict__ bb, float* __restrict__ outf,
    u16* __restrict__ outb) {
  const int row = blockIdx.x;
  const int tid = threadIdx.x;
  const int w = tid >> 6, lane = tid & 63;
  const int head = tid >> 4;
  float4 a0 = ((const float4*)(O0 + (size_t)row * 1024))[tid];
  float4 a1 = ((const float4*)(O1 + (size_t)row * 1024))[tid];
  const float inv = 1.f / (l0[row * 16 + head] + l1[row * 16 + head]);
  float4 v;
  v.x = (a0.x + a1.x) * inv;
  v.y = (a0.y + a1.y) * inv;
  v.z = (a0.z + a1.z) * inv;
  v.w = (a0.w + a1.w) * inv;
  float s = v.x + v.y + v.z + v.w;
  float s2 = v.x * v.x + v.y * v.y + v.z * v.z + v.w * v.w;
#pragma unroll
  for (int off = 32; off > 0; off >>= 1) {
    s += __shfl_xor(s, off);
    s2 += __shfl_xor(s2, off);
  }
  __shared__ float red[8];
  if (lane == 0) { red[w] = s; red[4 + w] = s2; }
  __syncthreads();
  s = red[0] + red[1] + red[2] + red[3];
  s2 = red[4] + red[5] + red[6] + red[7];
  const float mu = s * (1.f / 1024.f);
  const float var = s2 * (1.f / 1024.f) - mu * mu;
  const float rstd = rsqrtf(var + 1e-5f);
  float4 xr = ((const float4*)(xres + (size_t)row * 1024))[tid];
  float4 gv = ((const float4*)g)[tid];
  float4 bv = ((const float4*)bb)[tid];
  float4 o;
  o.x = xr.x + (v.x - mu) * rstd * gv.x + bv.x;
  o.y = xr.y + (v.y - mu) * rstd * gv.y + bv.y;
  o.z = xr.z + (v.z - mu) * rstd * gv.z + bv.z;
  o.w = xr.w + (v.w - mu) * rstd * gv.w + bv.w;
  ((float4*)(outf + (size_t)row * 1024))[tid] = o;
  u16x4 ob = { f2b(o.x), f2b(o.y), f2b(o.z), f2b(o.w) };
  *(u16x4*)(outb + (size_t)row * 1024 + (size_t)tid * 4) = ob;
}

// ---------------------------------------------------------------------------
// out = xres + LN(p0+p1+p2+p3 + bias)*g + b  (FFN2 split-K combine), fp32 out
__global__ __launch_bounds__(256) void ln_ffn_kernel(
    const u16* __restrict__ p0, const u16* __restrict__ p1,
    const u16* __restrict__ p2, const u16* __restrict__ p3,
    const float* __restrict__ bias, const float* __restrict__ xres,
    const float* __restrict__ g, const float* __restrict__ bb,
    float* __restrict__ outf) {
  const int row = blockIdx.x;
  const int tid = threadIdx.x;
  const int w = tid >> 6, lane = tid & 63;
  u16x4 a0 = ((const u16x4*)(p0 + (size_t)row * 1024))[tid];
  u16x4 a1 = ((const u16x4*)(p1 + (size_t)row * 1024))[tid];
  u16x4 a2 = ((const u16x4*)(p2 + (size_t)row * 1024))[tid];
  u16x4 a3 = ((const u16x4*)(p3 + (size_t)row * 1024))[tid];
  float4 bv4 = ((const float4*)bias)[tid];
  float4 v;
  v.x = (b2f(a0[0]) + b2f(a1[0])) + (b2f(a2[0]) + b2f(a3[0])) + bv4.x;
  v.y = (b2f(a0[1]) + b2f(a1[1])) + (b2f(a2[1]) + b2f(a3[1])) + bv4.y;
  v.z = (b2f(a0[2]) + b2f(a1[2])) + (b2f(a2[2]) + b2f(a3[2])) + bv4.z;
  v.w = (b2f(a0[3]) + b2f(a1[3])) + (b2f(a2[3]) + b2f(a3[3])) + bv4.w;
  float s = v.x + v.y + v.z + v.w;
  float s2 = v.x * v.x + v.y * v.y + v.z * v.z + v.w * v.w;
#pragma unroll
  for (int off = 32; off > 0; off >>= 1) {
    s += __shfl_xor(s, off);
    s2 += __shfl_xor(s2, off);
  }
  __shared__ float red[8];
  if (lane == 0) { red[w] = s; red[4 + w] = s2; }
  __syncthreads();
  s = red[0] + red[1] + red[2] + red[3];
  s2 = red[4] + red[5] + red[6] + red[7];
  const float mu = s * (1.f / 1024.f);
  const float var = s2 * (1.f / 1024.f) - mu * mu;
  const float rstd = rsqrtf(var + 1e-5f);
  float4 xr = ((const float4*)(xres + (size_t)row * 1024))[tid];
  float4 gv = ((const float4*)g)[tid];
  float4 bv = ((const float4*)bb)[tid];
  float4 o;
  o.x = xr.x + (v.x - mu) * rstd * gv.x + bv.x;
  o.y = xr.y + (v.y - mu) * rstd * gv.y + bv.y;
  o.z = xr.z + (v.z - mu) * rstd * gv.z + bv.z;
  o.w = xr.w + (v.w - mu) * rstd * gv.w + bv.w;
  ((float4*)(outf + (size_t)row * 1024))[tid] = o;
}

// ---------------------------------------------------------------------------
extern "C" void kernel_launch(void* const* d_in, const int* in_sizes, int n_in,
                              void* d_out, int out_size, void* d_ws, size_t ws_size,
                              hipStream_t stream) {
  const float* x     = (const float*)d_in[0];
  const float* w_qkv = (const float*)d_in[1];
  const float* ln1_g = (const float*)d_in[2];
  const float* ln1_b = (const float*)d_in[3];
  const float* w1    = (const float*)d_in[4];
  const float* b1    = (const float*)d_in[5];
  const float* w2    = (const float*)d_in[6];
  const float* b2    = (const float*)d_in[7];
  const float* ln2_g = (const float*)d_in[8];
  const float* ln2_b = (const float*)d_in[9];
  float* out = (float*)d_out;
  char* ws = (char*)d_ws;

  // workspace (lifetime-aliased; max end = 98,566,144 B):
  u16*   xb    = (u16*)(ws + 0);              // [0,8.4M)     dead after qkv gemm
  u16*   wqkvT = (u16*)(ws + 8388608);        // [8.4,14.7M)  dead after qkv gemm
  u16*   qkvb  = (u16*)(ws + 31457280);       // [31.5,56.6M) dead after attn
  u16*   vT    = (u16*)(ws + 56623104);       // [56.6,73.4M) dead after attn
  float* Op0   = (float*)(ws + 0);            // [0,16.8M)    attn partial 0 (over dead xb/wqkvT)
  float* Op1   = (float*)(ws + 73400320);     // [73.4,90.2M) attn partial 1
  float* lp    = (float*)(ws + 90177536);     // [90.2,90.7M) l partials (2x256KB)
  float* x1    = (float*)(ws + 31457280);     // [31.5,48.2M) over dead qkvb (after attn)
  u16*   x1b   = (u16*)(ws + 48234496);       // [48.2,56.6M) over dead qkvb; dead after FFN1
  u16*   w1T   = (u16*)(ws + 14680064);       // [14.7,23.1M) written after LN1 (over dead Op0)
  u16*   w2T   = (u16*)(ws + 23068672);       // [23.1,31.5M) written after LN1
  u16*   h1    = (u16*)(ws + 56623104);       // [56.6,90.2M) over dead vT+Op1
  u16*   fp0   = (u16*)(ws + 0);              // FFN2 partials (over dead Op0/lp/x1b)
  u16*   fp1   = (u16*)(ws + 8388608);
  u16*   fp2   = (u16*)(ws + 48234496);
  u16*   fp3   = (u16*)(ws + 90177536);

  convert_bf16_kernel<<<4096, 256, 0, stream>>>(x, xb);
  transpose_bf16_kernel<<<dim3(96, 32), 256, 0, stream>>>(w_qkv, wqkvT, 1024, 3072);

  // qkv: M=4096 N=3072 K=1024 -> 16x12 = 192 blocks
  gemm256_kernel<<<dim3(192, 1), 512, 0, stream>>>(
      xb, wqkvT, nullptr, qkvb, 4096, 3072, 1024, 0,
      nullptr, nullptr, nullptr);
  transpose_v_kernel<<<dim3(32, 32), 256, 0, stream>>>(qkvb, vT);
  attn_kernel<<<dim3(32, 16, 2), 256, 0, stream>>>(qkvb, vT, Op0, Op1, lp);

  ln_attn_kernel<<<4096, 256, 0, stream>>>(
      Op0, Op1, lp, lp + 4096 * 16, x, ln1_g, ln1_b, x1, x1b);

  transpose_bf16_kernel<<<dim3(128, 32), 256, 0, stream>>>(w1, w1T, 1024, 4096);
  transpose_bf16_kernel<<<dim3(32, 128), 256, 0, stream>>>(w2, w2T, 4096, 1024);

  // FFN1: M=4096 N=4096 K=1024 -> 256 blocks
  gemm256_kernel<<<dim3(256, 1), 512, 0, stream>>>(
      x1b, w1T, b1, h1, 4096, 4096, 1024, 1,
      nullptr, nullptr, nullptr);
  // FFN2: M=4096 N=1024 K=4096, split-K=4 -> 64x4 blocks
  gemm256_kernel<<<dim3(64, 4), 512, 0, stream>>>(
      h1, w2T, nullptr, fp0, 4096, 1024, 4096, 0,
      fp1, fp2, fp3);

  ln_ffn_kernel<<<4096, 256, 0, stream>>>(
      fp0, fp1, fp2, fp3, b2, x1, ln2_g, ln2_b, out);
}

// Round 5
// 320.728 us; speedup vs baseline: 1.0856x; 1.0155x over previous
//
#include <hip/hip_runtime.h>

// ---------------------------------------------------------------------------
// TransformerBlock: x:[2,2048,1024] fp32
//   qkv = x @ w_qkv;  attention (scale 1/sqrt(1024));  x = x + LN(attn_out)
//   ff  = relu(x@w1+b1)@w2+b2;  out = x + LN(ff)
// R12: GEMM barrier diet. R11's GTILE had 4 full-block barriers per BK=32
//     tile (128/pass); 3 of the 4 were provably unnecessary (phase-b reads
//     the same buffer; read-validity comes from the PREVIOUS tile's end
//     barrier). New structure: 3 LDS buffers (96KB), stage k-tile t+2 into
//     buf (t+2)%3 during tile t, ONE end-of-tile barrier preceded by
//     counted vmcnt(4) (retires t+1's DMAs, keeps t+2's in flight; drains
//     to 0 only at tile 30). Per tile: {read B+A-lo | stage A | lgkm+schedbar
//     | 16 MFMA | read A-hi | stage B | lgkm | 16 MFMA | vmcnt(4) | barrier}.
//     Waves self-skew between barriers -> 2 waves/SIMD anti-phase
//     (LDS-read || MFMA, the m114 mechanism). Barriers 129 -> 33 per pass.
//     attn/LN/transposes unchanged from R11 (attn = R8 best-measured).
// ---------------------------------------------------------------------------

typedef unsigned short u16;
typedef unsigned int u32;
typedef __bf16 bf16x8 __attribute__((ext_vector_type(8)));
typedef float f32x4 __attribute__((ext_vector_type(4)));
typedef float f32x16 __attribute__((ext_vector_type(16)));
typedef u32 u32x4 __attribute__((ext_vector_type(4)));
typedef u16 u16x4 __attribute__((ext_vector_type(4)));

__device__ __forceinline__ u16 f2b(float f) {
  u32 u = __builtin_bit_cast(u32, f);
  u += 0x7fffu + ((u >> 16) & 1u);       // RNE
  return (u16)(u >> 16);
}
__device__ __forceinline__ float b2f(u16 u) {
  return __builtin_bit_cast(float, (u32)u << 16);
}

// pack 2 fp32 -> 1 dword of 2 bf16 (RNE), lo in low half
__device__ __forceinline__ u32 cvtpk(float lo, float hi) {
  u32 r;
  asm("v_cvt_pk_bf16_f32 %0, %1, %2" : "=v"(r) : "v"(lo), "v"(hi));
  return r;
}

// async global->LDS DMA, 16B per lane. LDS dest = wave-uniform base + lane*16.
__device__ __forceinline__ void gld_lds16(const u16* g, u16* l) {
  __builtin_amdgcn_global_load_lds(
      (const __attribute__((address_space(1))) u32*)g,
      (__attribute__((address_space(3))) u32*)l, 16, 0, 0);
}

// ---------------------------------------------------------------------------
__global__ __launch_bounds__(256) void convert_bf16_kernel(
    const float* __restrict__ in, u16* __restrict__ out) {
  const int idx = blockIdx.x * 256 + threadIdx.x;
  float4 v = ((const float4*)in)[idx];
  u16x4 o = { f2b(v.x), f2b(v.y), f2b(v.z), f2b(v.w) };
  ((u16x4*)out)[idx] = o;
}

// fp32[R][C] -> bf16 out[C][R]
__global__ __launch_bounds__(256) void transpose_bf16_kernel(
    const float* __restrict__ in, u16* __restrict__ out, int R, int C) {
  __shared__ float tile[32][33];
  const int cb = blockIdx.x * 32, rb = blockIdx.y * 32;
  const int c = threadIdx.x & 31;
  const int r0 = threadIdx.x >> 5;
#pragma unroll
  for (int rr = 0; rr < 32; rr += 8)
    tile[r0 + rr][c] = in[(size_t)(rb + r0 + rr) * C + cb + c];
  __syncthreads();
#pragma unroll
  for (int rr = 0; rr < 32; rr += 8)
    out[(size_t)(cb + r0 + rr) * R + rb + c] = f2b(tile[c][r0 + rr]);
}

// V part of qkv [s][d] -> vt[bh][d][s]  (bf16 copy-transpose, 64x64 tiles)
__global__ __launch_bounds__(256) void transpose_v_kernel(
    const u16* __restrict__ qkv, u16* __restrict__ vt) {
  __shared__ u16 t[64][70];
  const int bh = blockIdx.x, st = blockIdx.y;
  const int b = bh >> 4, nh = bh & 15;
  const int s0 = st * 64;
  const int r = threadIdx.x >> 3, c = (threadIdx.x & 7) << 3;
  const u16* src = qkv + (size_t)(b * 2048 + s0) * 3072 + 2048 + nh * 64;
#pragma unroll
  for (int rr = 0; rr < 64; rr += 32)
    *(u32x4*)&t[r + rr][c] = *(const u32x4*)(src + (size_t)(r + rr) * 3072 + c);
  __syncthreads();
  u16* dst = vt + ((size_t)bh * 64) * 2048 + s0;
#pragma unroll
  for (int rr = 0; rr < 64; rr += 32) {
    const int d = r + rr;
    u16 tmp[8];
#pragma unroll
    for (int j = 0; j < 8; ++j) tmp[j] = t[c + j][d];
    *(u32x4*)(dst + (size_t)d * 2048 + c) = *(u32x4*)tmp;
  }
}

// ---------------------------------------------------------------------------
// C[M,N] = A[M,K](bf16) @ Bt[N,K](bf16)^T, fp32 accum, bf16 out.
// 256x256 tile, BK=32, 8 waves (wm: 128 rows; wn: 64 cols), 3 LDS buffers.
// K-per-block hardcoded 1024 (32 tiles); split-K via gridDim.y (z*1024 off).
// One barrier per tile; vmcnt(4) counted ledger (see R12 header).
// Requires M%256==0, N%256==0, gridDim.x%8==0.
#define GT(BUF, SBUF, T2, VM)                                                 \
  {                                                                           \
    const u16(*Ab)[32] = As[BUF];                                             \
    const u16(*Bb)[32] = Bs[BUF];                                             \
    bf16x8 af[4], bfr[4];                                                     \
    _Pragma("unroll") for (int nr = 0; nr < 4; ++nr)                          \
        bfr[nr] = *(const bf16x8*)&Bb[wn * 64 + nr * 16 + l16][cRd];          \
    _Pragma("unroll") for (int mr = 0; mr < 4; ++mr)                          \
        af[mr] = *(const bf16x8*)&Ab[wm * 128 + mr * 16 + l16][cRd];          \
    if ((T2) >= 0) {                                                          \
      gld_lds16(Ag + (size_t)(T2) * 32,         &As[SBUF][w * 16][0]);        \
      gld_lds16(Ag + rstep + (size_t)(T2) * 32, &As[SBUF][128 + w * 16][0]);  \
    }                                                                         \
    asm volatile("s_waitcnt lgkmcnt(0)" ::: "memory");                        \
    __builtin_amdgcn_sched_barrier(0);                                        \
    __builtin_amdgcn_s_setprio(1);                                            \
    _Pragma("unroll") for (int mr = 0; mr < 4; ++mr)                          \
        _Pragma("unroll") for (int nr = 0; nr < 4; ++nr)                      \
            acc[mr][nr] = __builtin_amdgcn_mfma_f32_16x16x32_bf16(            \
                af[mr], bfr[nr], acc[mr][nr], 0, 0, 0);                       \
    __builtin_amdgcn_s_setprio(0);                                            \
    _Pragma("unroll") for (int mr = 0; mr < 4; ++mr)                          \
        af[mr] = *(const bf16x8*)&Ab[wm * 128 + 64 + mr * 16 + l16][cRd];     \
    if ((T2) >= 0) {                                                          \
      gld_lds16(Bg + (size_t)(T2) * 32,         &Bs[SBUF][w * 16][0]);        \
      gld_lds16(Bg + rstep + (size_t)(T2) * 32, &Bs[SBUF][128 + w * 16][0]);  \
    }                                                                         \
    asm volatile("s_waitcnt lgkmcnt(0)" ::: "memory");                        \
    __builtin_amdgcn_sched_barrier(0);                                        \
    __builtin_amdgcn_s_setprio(1);                                            \
    _Pragma("unroll") for (int mr = 0; mr < 4; ++mr)                          \
        _Pragma("unroll") for (int nr = 0; nr < 4; ++nr)                      \
            acc[4 + mr][nr] = __builtin_amdgcn_mfma_f32_16x16x32_bf16(        \
                af[mr], bfr[nr], acc[4 + mr][nr], 0, 0, 0);                   \
    __builtin_amdgcn_s_setprio(0);                                            \
    if ((VM) == 4) asm volatile("s_waitcnt vmcnt(4)" ::: "memory");           \
    else if ((VM) == 0) asm volatile("s_waitcnt vmcnt(0)" ::: "memory");      \
    if ((VM) >= 0) __builtin_amdgcn_s_barrier();                              \
  }

__global__ __launch_bounds__(512) void gemm256_kernel(
    const u16* __restrict__ A, const u16* __restrict__ Bt,
    const float* __restrict__ bias, u16* __restrict__ Cb,
    int M, int N, int K, int relu,
    u16* __restrict__ Cb1, u16* __restrict__ Cb2, u16* __restrict__ Cb3) {
  // XCD-chunked bijective swizzle (gridDim.x % 8 == 0): consecutive blocks in
  // an XCD share the A row-panel (L2-resident), sweep n.
  const int nN = N >> 8;
  const int lin = (blockIdx.x & 7) * ((int)gridDim.x >> 3) + (blockIdx.x >> 3);
  const int m0 = (lin / nN) << 8;
  const int n0 = (lin % nN) << 8;
  const int z = blockIdx.y;
  if (z == 1) Cb = Cb1; else if (z == 2) Cb = Cb2; else if (z == 3) Cb = Cb3;

  const int tid = threadIdx.x;
  const int w = tid >> 6, lane = tid & 63;
  const int quad = lane >> 4, l16 = lane & 15;
  const int wm = w >> 2, wn = w & 3;

  __shared__ u16 As[3][256][32];      // 48KB: K-cols t*32..t*32+31, swizzled
  __shared__ u16 Bs[3][256][32];      // 48KB

  f32x4 acc[8][4];
#pragma unroll
  for (int i = 0; i < 8; ++i)
#pragma unroll
    for (int j = 0; j < 4; ++j) acc[i][j] = {0.f, 0.f, 0.f, 0.f};

  // staging: per gld_lds, wave w covers 16 rows (rows w*16+(l>>2), +issue*128);
  // pre-swizzled global chunk = (l&3) ^ (row&3) so LDS[row][c] holds global
  // chunk c ^ (row&3)  (involution; reads apply the same XOR).
  const int srow = lane >> 2;                               // 0..15
  const int scol = (((lane & 3) ^ (srow & 3)) << 3);        // u16 units
  const u16* Ag = A + (size_t)(m0 + w * 16 + srow) * K + (size_t)z * 1024 + scol;
  const u16* Bg = Bt + (size_t)(n0 + w * 16 + srow) * K + (size_t)z * 1024 + scol;
  const size_t rstep = (size_t)128 * K;

  // fragment-read swizzled chunk: row&3 == l16&3 for all frag rows
  const int cRd = ((quad ^ (l16 & 3)) << 3);                // u16 units

  // prologue: stage k-tiles 0 and 1; vmcnt(4) -> tile 0 resident, 1 in flight
  gld_lds16(Ag,              &As[0][w * 16][0]);
  gld_lds16(Ag + rstep,      &As[0][128 + w * 16][0]);
  gld_lds16(Bg,              &Bs[0][w * 16][0]);
  gld_lds16(Bg + rstep,      &Bs[0][128 + w * 16][0]);
  gld_lds16(Ag + 32,         &As[1][w * 16][0]);
  gld_lds16(Ag + rstep + 32, &As[1][128 + w * 16][0]);
  gld_lds16(Bg + 32,         &Bs[1][w * 16][0]);
  gld_lds16(Bg + rstep + 32, &Bs[1][128 + w * 16][0]);
  asm volatile("s_waitcnt vmcnt(4)" ::: "memory");
  __builtin_amdgcn_s_barrier();

  // tiles 0..29: buf cycles 0,1,2; stage k-tile t+2 into buf (t+2)%3
  for (int tt = 0; tt < 10; ++tt) {
    const int t = tt * 3;
    GT(0, 2, t + 2, 4)
    GT(1, 0, t + 3, 4)
    GT(2, 1, t + 4, 4)
  }
  GT(0, 0, -1, 0)    // tile 30: no stage; drain tile 31's DMAs
  GT(1, 0, -1, -1)   // tile 31: no stage, no barrier

  // epilogue: wave writes 128 rows x 64 cols
#pragma unroll
  for (int mr = 0; mr < 8; ++mr) {
    const int row = m0 + wm * 128 + mr * 16 + quad * 4;
#pragma unroll
    for (int nr = 0; nr < 4; ++nr) {
      const int col = n0 + wn * 64 + nr * 16 + l16;
      const float bv = bias ? bias[col] : 0.f;
#pragma unroll
      for (int r = 0; r < 4; ++r) {
        float v = acc[mr][nr][r] + bv;
        if (relu) v = fmaxf(v, 0.f);
        Cb[(size_t)(row + r) * N + col] = f2b(v);
      }
    }
  }
}

// ---------------------------------------------------------------------------
// Flash attention (R8 version), fixed-max softmax, split over keys (kz 0/1).
// Block = (bh, 128 q-rows, 1024-key range); 4 waves x 32 q-rows.
// 32x32x16 MFMA, swapped QK^T (S^T = K.Q^T): lane owns query = lane&31.
// P fragments built in-register via cvt_pk_bf16 + permlane32_swap.
// Writes UNNORMALIZED O partial (fp32) + l partial; LN1 combines.
__global__ __launch_bounds__(256, 4) void attn_kernel(
    const u16* __restrict__ qkv, const u16* __restrict__ vt,
    float* __restrict__ Op0, float* __restrict__ Op1,
    float* __restrict__ lpart) {
  const int bh = blockIdx.x;          // b*16 + nh
  const int qt = blockIdx.y;          // 0..15
  const int kz = blockIdx.z;          // 0..1
  const int b = bh >> 4, nh = bh & 15;
  const int tid = threadIdx.x;
  const int w = tid >> 6, lane = tid & 63;
  const int l32 = lane & 31, hi = lane >> 5;
  const float c2 = 0.04508422f;       // log2(e)/sqrt(1024)

  __shared__ u16 KS[64][64];          // K tile [key][d], chunk-swizzled
  __shared__ u16 VS[64][64];          // V^T tile [d][key], chunk-swizzled

  const size_t rs = 3072;
  const u16* qbase = qkv + (size_t)b * 2048 * rs + nh * 64;
  const u16* kbase = qbase + 1024;
  const u16* vbase = vt + (size_t)bh * 64 * 2048;
  const int q0 = qt * 128;
  const int k0beg = kz * 1024;

  // Q fragments to registers, pre-scaled by c2.
  bf16x8 aq[4];
  {
    const u16* qrow = qbase + (size_t)(q0 + w * 32 + l32) * rs + hi * 8;
#pragma unroll
    for (int ds = 0; ds < 4; ++ds) {
      u32x4 v = *(const u32x4*)(qrow + ds * 16);
      u16 ti[8], to[8];
      *(u32x4*)ti = v;
#pragma unroll
      for (int j = 0; j < 8; ++j) to[j] = f2b(b2f(ti[j]) * c2);
      u32x4 pk = *(u32x4*)to;
      aq[ds] = __builtin_bit_cast(bf16x8, pk);
    }
  }

  f32x16 Oacc[2];
#pragma unroll
  for (int dn = 0; dn < 2; ++dn)
#pragma unroll
    for (int i = 0; i < 16; ++i) Oacc[dn][i] = 0.f;
  float ls[4] = {0.f, 0.f, 0.f, 0.f};

  // staging map: lane l -> row (l>>3), 16B chunk (l&7) ^ (row&7)  (XOR swz)
  const int srow = lane >> 3;                       // 0..7
  const int scol = ((lane & 7) ^ srow) << 3;        // u16 units, swizzled

#pragma unroll 1
  for (int t = 0; t < 16; ++t) {
    const int k0 = k0beg + t * 64;
    __syncthreads();                  // all waves done with prev tile
    gld_lds16(kbase + (size_t)(k0 + w * 16 + srow) * rs + scol,       &KS[w * 16][0]);
    gld_lds16(kbase + (size_t)(k0 + w * 16 + 8 + srow) * rs + scol,   &KS[w * 16 + 8][0]);
    gld_lds16(vbase + (size_t)(w * 16 + srow) * 2048 + k0 + scol,     &VS[w * 16][0]);
    gld_lds16(vbase + (size_t)(w * 16 + 8 + srow) * 2048 + k0 + scol, &VS[w * 16 + 8][0]);
    __syncthreads();                  // barrier drains vmcnt -> DMA visible

    // S^T = K . Q^T : lane holds S^T[key = 32*jt + crow(r,hi)][query = l32]
    f32x16 S[2];
#pragma unroll
    for (int jt = 0; jt < 2; ++jt)
#pragma unroll
      for (int i = 0; i < 16; ++i) S[jt][i] = 0.f;
#pragma unroll
    for (int jt = 0; jt < 2; ++jt) {
      const int krow = jt * 32 + l32;
#pragma unroll
      for (int ds = 0; ds < 4; ++ds) {
        bf16x8 kv = *(const bf16x8*)&KS[krow][((2 * ds + hi) ^ (krow & 7)) << 3];
        S[jt] = __builtin_amdgcn_mfma_f32_32x32x16_bf16(kv, aq[ds], S[jt], 0, 0, 0);
      }
    }

    // p = exp2(S^T); build PV A-fragments in-register.
    bf16x8 pa[4];
#pragma unroll
    for (int jt = 0; jt < 2; ++jt) {
      float p[16];
#pragma unroll
      for (int r = 0; r < 16; ++r) {
        p[r] = exp2f(S[jt][r]);
        ls[r & 3] += p[r];
      }
#pragma unroll
      for (int bq = 0; bq < 2; ++bq) {
        u32 x0 = cvtpk(p[8 * bq + 0], p[8 * bq + 1]);
        u32 y0 = cvtpk(p[8 * bq + 4], p[8 * bq + 5]);
        u32 x1 = cvtpk(p[8 * bq + 2], p[8 * bq + 3]);
        u32 y1 = cvtpk(p[8 * bq + 6], p[8 * bq + 7]);
        asm("v_permlane32_swap_b32 %0, %1" : "+v"(x0), "+v"(y0));
        asm("v_permlane32_swap_b32 %0, %1" : "+v"(x1), "+v"(y1));
        u32x4 dw = {x0, x1, y0, y1};  // keys {0,1},{2,3},{4,5},{6,7} (+8hi)
        pa[2 * jt + bq] = __builtin_bit_cast(bf16x8, dw);
      }
    }

    // O += P V : lane holds O[query = crow(r,hi)][d = dn*32 + l32]
#pragma unroll
    for (int dn = 0; dn < 2; ++dn) {
      const int vrow = dn * 32 + l32;
#pragma unroll
      for (int ks = 0; ks < 4; ++ks) {
        bf16x8 vv = *(const bf16x8*)&VS[vrow][((2 * ks + hi) ^ (vrow & 7)) << 3];
        Oacc[dn] = __builtin_amdgcn_mfma_f32_32x32x16_bf16(pa[ks], vv, Oacc[dn], 0, 0, 0);
      }
    }
  }

  // l: per-lane partial covers this hi's keys; add partner half (lane^32)
  float lsum = (ls[0] + ls[1]) + (ls[2] + ls[3]);
  const float ltot = lsum + __shfl_xor(lsum, 32);

  float* opart = kz ? Op1 : Op0;
  float* obase = opart + (size_t)b * 2048 * 1024 + (size_t)nh * 64;
  float* lbase = lpart + (size_t)kz * 4096 * 16 + (size_t)b * 2048 * 16 + nh;
#pragma unroll
  for (int r = 0; r < 16; ++r) {
    const int qrow = q0 + w * 32 + (r & 3) + 8 * (r >> 2) + 4 * hi;
#pragma unroll
    for (int dn = 0; dn < 2; ++dn)
      obase[(size_t)qrow * 1024 + dn * 32 + l32] = Oacc[dn][r];
  }
  if (lane < 32) lbase[(size_t)(q0 + w * 32 + l32) * 16] = ltot;
}

// ---------------------------------------------------------------------------
// x1 = xres + LN((O0+O1)/(l0+l1))*g + b ; writes fp32 + bf16
__global__ __launch_bounds__(256) void ln_attn_kernel(
    const float* __restrict__ O0, const float* __restrict__ O1,
    const float* __restrict__ l0, const float* __restrict__ l1,
    const float* __restrict__ xres, const float* __restrict__ g,
    const float* __restrict__ bb, float* __restrict__ outf,
    u16* __restrict__ outb) {
  const int row = blockIdx.x;
  const int tid = threadIdx.x;
  const int w = tid >> 6, lane = tid & 63;
  const int head = tid >> 4;
  float4 a0 = ((const float4*)(O0 + (size_t)row * 1024))[tid];
  float4 a1 = ((const float4*)(O1 + (size_t)row * 1024))[tid];
  const float inv = 1.f / (l0[row * 16 + head] + l1[row * 16 + head]);
  float4 v;
  v.x = (a0.x + a1.x) * inv;
  v.y = (a0.y + a1.y) * inv;
  v.z = (a0.z + a1.z) * inv;
  v.w = (a0.w + a1.w) * inv;
  float s = v.x + v.y + v.z + v.w;
  float s2 = v.x * v.x + v.y * v.y + v.z * v.z + v.w * v.w;
#pragma unroll
  for (int off = 32; off > 0; off >>= 1) {
    s += __shfl_xor(s, off);
    s2 += __shfl_xor(s2, off);
  }
  __shared__ float red[8];
  if (lane == 0) { red[w] = s; red[4 + w] = s2; }
  __syncthreads();
  s = red[0] + red[1] + red[2] + red[3];
  s2 = red[4] + red[5] + red[6] + red[7];
  const float mu = s * (1.f / 1024.f);
  const float var = s2 * (1.f / 1024.f) - mu * mu;
  const float rstd = rsqrtf(var + 1e-5f);
  float4 xr = ((const float4*)(xres + (size_t)row * 1024))[tid];
  float4 gv = ((const float4*)g)[tid];
  float4 bv = ((const float4*)bb)[tid];
  float4 o;
  o.x = xr.x + (v.x - mu) * rstd * gv.x + bv.x;
  o.y = xr.y + (v.y - mu) * rstd * gv.y + bv.y;
  o.z = xr.z + (v.z - mu) * rstd * gv.z + bv.z;
  o.w = xr.w + (v.w - mu) * rstd * gv.w + bv.w;
  ((float4*)(outf + (size_t)row * 1024))[tid] = o;
  u16x4 ob = { f2b(o.x), f2b(o.y), f2b(o.z), f2b(o.w) };
  *(u16x4*)(outb + (size_t)row * 1024 + (size_t)tid * 4) = ob;
}

// ---------------------------------------------------------------------------
// out = xres + LN(p0+p1+p2+p3 + bias)*g + b  (FFN2 split-K combine), fp32 out
__global__ __launch_bounds__(256) void ln_ffn_kernel(
    const u16* __restrict__ p0, const u16* __restrict__ p1,
    const u16* __restrict__ p2, const u16* __restrict__ p3,
    const float* __restrict__ bias, const float* __restrict__ xres,
    const float* __restrict__ g, const float* __restrict__ bb,
    float* __restrict__ outf) {
  const int row = blockIdx.x;
  const int tid = threadIdx.x;
  const int w = tid >> 6, lane = tid & 63;
  u16x4 a0 = ((const u16x4*)(p0 + (size_t)row * 1024))[tid];
  u16x4 a1 = ((const u16x4*)(p1 + (size_t)row * 1024))[tid];
  u16x4 a2 = ((const u16x4*)(p2 + (size_t)row * 1024))[tid];
  u16x4 a3 = ((const u16x4*)(p3 + (size_t)row * 1024))[tid];
  float4 bv4 = ((const float4*)bias)[tid];
  float4 v;
  v.x = (b2f(a0[0]) + b2f(a1[0])) + (b2f(a2[0]) + b2f(a3[0])) + bv4.x;
  v.y = (b2f(a0[1]) + b2f(a1[1])) + (b2f(a2[1]) + b2f(a3[1])) + bv4.y;
  v.z = (b2f(a0[2]) + b2f(a1[2])) + (b2f(a2[2]) + b2f(a3[2])) + bv4.z;
  v.w = (b2f(a0[3]) + b2f(a1[3])) + (b2f(a2[3]) + b2f(a3[3])) + bv4.w;
  float s = v.x + v.y + v.z + v.w;
  float s2 = v.x * v.x + v.y * v.y + v.z * v.z + v.w * v.w;
#pragma unroll
  for (int off = 32; off > 0; off >>= 1) {
    s += __shfl_xor(s, off);
    s2 += __shfl_xor(s2, off);
  }
  __shared__ float red[8];
  if (lane == 0) { red[w] = s; red[4 + w] = s2; }
  __syncthreads();
  s = red[0] + red[1] + red[2] + red[3];
  s2 = red[4] + red[5] + red[6] + red[7];
  const float mu = s * (1.f / 1024.f);
  const float var = s2 * (1.f / 1024.f) - mu * mu;
  const float rstd = rsqrtf(var + 1e-5f);
  float4 xr = ((const float4*)(xres + (size_t)row * 1024))[tid];
  float4 gv = ((const float4*)g)[tid];
  float4 bv = ((const float4*)bb)[tid];
  float4 o;
  o.x = xr.x + (v.x - mu) * rstd * gv.x + bv.x;
  o.y = xr.y + (v.y - mu) * rstd * gv.y + bv.y;
  o.z = xr.z + (v.z - mu) * rstd * gv.z + bv.z;
  o.w = xr.w + (v.w - mu) * rstd * gv.w + bv.w;
  ((float4*)(outf + (size_t)row * 1024))[tid] = o;
}

// ---------------------------------------------------------------------------
extern "C" void kernel_launch(void* const* d_in, const int* in_sizes, int n_in,
                              void* d_out, int out_size, void* d_ws, size_t ws_size,
                              hipStream_t stream) {
  const float* x     = (const float*)d_in[0];
  const float* w_qkv = (const float*)d_in[1];
  const float* ln1_g = (const float*)d_in[2];
  const float* ln1_b = (const float*)d_in[3];
  const float* w1    = (const float*)d_in[4];
  const float* b1    = (const float*)d_in[5];
  const float* w2    = (const float*)d_in[6];
  const float* b2    = (const float*)d_in[7];
  const float* ln2_g = (const float*)d_in[8];
  const float* ln2_b = (const float*)d_in[9];
  float* out = (float*)d_out;
  char* ws = (char*)d_ws;

  // workspace (lifetime-aliased; max end = 98,566,144 B):
  u16*   xb    = (u16*)(ws + 0);              // [0,8.4M)     dead after qkv gemm
  u16*   wqkvT = (u16*)(ws + 8388608);        // [8.4,14.7M)  dead after qkv gemm
  u16*   qkvb  = (u16*)(ws + 31457280);       // [31.5,56.6M) dead after attn
  u16*   vT    = (u16*)(ws + 56623104);       // [56.6,73.4M) dead after attn
  float* Op0   = (float*)(ws + 0);            // [0,16.8M)    attn partial 0 (over dead xb/wqkvT)
  float* Op1   = (float*)(ws + 73400320);     // [73.4,90.2M) attn partial 1
  float* lp    = (float*)(ws + 90177536);     // [90.2,90.7M) l partials (2x256KB)
  float* x1    = (float*)(ws + 31457280);     // [31.5,48.2M) over dead qkvb (after attn)
  u16*   x1b   = (u16*)(ws + 48234496);       // [48.2,56.6M) over dead qkvb; dead after FFN1
  u16*   w1T   = (u16*)(ws + 14680064);       // [14.7,23.1M) written after LN1 (over dead Op0)
  u16*   w2T   = (u16*)(ws + 23068672);       // [23.1,31.5M) written after LN1
  u16*   h1    = (u16*)(ws + 56623104);       // [56.6,90.2M) over dead vT+Op1
  u16*   fp0   = (u16*)(ws + 0);              // FFN2 partials (over dead Op0/lp/x1b)
  u16*   fp1   = (u16*)(ws + 8388608);
  u16*   fp2   = (u16*)(ws + 48234496);
  u16*   fp3   = (u16*)(ws + 90177536);

  convert_bf16_kernel<<<4096, 256, 0, stream>>>(x, xb);
  transpose_bf16_kernel<<<dim3(96, 32), 256, 0, stream>>>(w_qkv, wqkvT, 1024, 3072);

  // qkv: M=4096 N=3072 K=1024 -> 16x12 = 192 blocks
  gemm256_kernel<<<dim3(192, 1), 512, 0, stream>>>(
      xb, wqkvT, nullptr, qkvb, 4096, 3072, 1024, 0,
      nullptr, nullptr, nullptr);
  transpose_v_kernel<<<dim3(32, 32), 256, 0, stream>>>(qkvb, vT);
  attn_kernel<<<dim3(32, 16, 2), 256, 0, stream>>>(qkvb, vT, Op0, Op1, lp);

  ln_attn_kernel<<<4096, 256, 0, stream>>>(
      Op0, Op1, lp, lp + 4096 * 16, x, ln1_g, ln1_b, x1, x1b);

  transpose_bf16_kernel<<<dim3(128, 32), 256, 0, stream>>>(w1, w1T, 1024, 4096);
  transpose_bf16_kernel<<<dim3(32, 128), 256, 0, stream>>>(w2, w2T, 4096, 1024);

  // FFN1: M=4096 N=4096 K=1024 -> 256 blocks
  gemm256_kernel<<<dim3(256, 1), 512, 0, stream>>>(
      x1b, w1T, b1, h1, 4096, 4096, 1024, 1,
      nullptr, nullptr, nullptr);
  // FFN2: M=4096 N=1024 K=4096, split-K=4 -> 64x4 blocks
  gemm256_kernel<<<dim3(64, 4), 512, 0, stream>>>(
      h1, w2T, nullptr, fp0, 4096, 1024, 4096, 0,
      fp1, fp2, fp3);

  ln_ffn_kernel<<<4096, 256, 0, stream>>>(
      fp0, fp1, fp2, fp3, b2, x1, ln2_g, ln2_b, out);
}